// Round 5
// baseline (4713.932 us; speedup 1.0000x reference)
//
#include <hip/hip_runtime.h>
#include <math.h>

// B=32, L=1024, D=256, G=768
#define NROWS 32768  // B*L

typedef float v4 __attribute__((ext_vector_type(4)));
typedef _Float16 h2 __attribute__((ext_vector_type(2)));

__device__ __forceinline__ float geluf(float x){ return 0.5f*x*(1.0f+erff(x*0.70710678118654752f)); }
__device__ __forceinline__ float sigm(float x){ return 1.0f/(1.0f+expf(-x)); }

__device__ __forceinline__ float dot2(h2 a, h2 b, float c){
#if __has_builtin(__builtin_amdgcn_fdot2)
    return __builtin_amdgcn_fdot2(a, b, c, false);
#else
    return c + (float)a.x*(float)b.x + (float)a.y*(float)b.y;
#endif
}

// barrier that does NOT drain vmcnt: LDS visibility only. Global prefetch
// loads / output stores stay in flight across it.
__device__ __forceinline__ void wg_barrier(){
    asm volatile("s_waitcnt lgkmcnt(0)" ::: "memory");
    __builtin_amdgcn_s_barrier();
    __builtin_amdgcn_sched_barrier(0);
}

// ---------------- start embed: sh[b,d] ----------------
__global__ __launch_bounds__(256) void k_start_embed(
    const float* __restrict__ ne, const float* __restrict__ w0, const float* __restrict__ b0,
    const float* __restrict__ w1, const float* __restrict__ b1,
    const float* __restrict__ w2, const float* __restrict__ b2,
    float* __restrict__ sh)
{
    __shared__ __align__(16) float encL[1024];
    __shared__ __align__(16) float g1[256];
    __shared__ __align__(16) float g2[256];
    int b = blockIdx.x, t = threadIdx.x;
    for (int i = t; i < 1024; i += 256) encL[i] = ne[b*1024 + i];
    __syncthreads();
    const float4* wr = (const float4*)(w0 + (size_t)t*1024);
    const float4* e4 = (const float4*)encL;
    float a0=0,a1=0,a2=0,a3=0;
    #pragma unroll 8
    for (int k = 0; k < 256; ++k){ float4 w = wr[k], e = e4[k];
        a0 += w.x*e.x; a1 += w.y*e.y; a2 += w.z*e.z; a3 += w.w*e.w; }
    float t1 = a0+a1+a2+a3 + b0[t];
    float res = t1;
    g1[t] = geluf(t1);
    __syncthreads();
    const float4* w1r = (const float4*)(w1 + (size_t)t*256);
    const float4* g14 = (const float4*)g1;
    a0=a1=a2=a3=0.f;
    #pragma unroll 8
    for (int k = 0; k < 64; ++k){ float4 w = w1r[k], e = g14[k];
        a0 += w.x*e.x; a1 += w.y*e.y; a2 += w.z*e.z; a3 += w.w*e.w; }
    g2[t] = geluf(a0+a1+a2+a3 + b1[t]);
    __syncthreads();
    const float4* w2r = (const float4*)(w2 + (size_t)t*256);
    const float4* g24 = (const float4*)g2;
    a0=a1=a2=a3=0.f;
    #pragma unroll 8
    for (int k = 0; k < 64; ++k){ float4 w = w2r[k], e = g24[k];
        a0 += w.x*e.x; a1 += w.y*e.y; a2 += w.z*e.z; a3 += w.w*e.w; }
    sh[b*256 + t] = a0+a1+a2+a3 + b2[t] + res;
}

// permuted f16 index within an hbuf row for hidden dim:
// dim = (hi:2)(mid:3)(lo:3) -> idx = mid*32 + hi*8 + lo  (bijective).
// Float4 slot s = mid*4 + hi holds dims hi*64 + mid*8 .. +8, so the four
// K-quarters' ds_read_b128 of slot kk*4+q are CONSECUTIVE 16B -> distinct
// banks (was 128B-strided same-bank, 4-way conflict).
__device__ __forceinline__ int hperm(int dim){
    return ((dim >> 3) & 7)*32 + ((dim >> 6) << 3) + (dim & 7);
}

// ---------------- GRU scan v5: register-resident f16 weights, K-quarter split ----------------
// One WG per batch, 1024 threads (16 waves, 4/SIMD -> hard 128-VGPR cap).
// Thread (d = t>>2, q = t&3) owns gate rows d (r), d+256 (z), d+512 (n)
// restricted to K-quarter [q*64, q*64+64): 3 x 32 h2 = 96 weight VGPRs ->
// fits under 128, NO spill. Quarter partials combined with __shfl_xor(.,1)
// and (.,2) (quad-local -> DPP). h kept f16 in LDS (permuted layout above),
// fp32 master h in a register; one lgkm-only barrier per step.
template<int LAYER>
__global__ __launch_bounds__(1024) void k_gru_scan(
    const float* __restrict__ w_hh, const float* __restrict__ b_hh,
    const float* __restrict__ w_ih0, const float* __restrict__ b_ih0,
    const float* __restrict__ xp1,
    const int*   __restrict__ trg,
    const float* __restrict__ sh,
    float* __restrict__ out)
{
    __shared__ __align__(16) _Float16 hbuf[2][256];
    __shared__ __align__(16) float bitL[1024];
    int b = blockIdx.x, t = threadIdx.x;
    int d = t >> 2, q = t & 3;

    if (LAYER == 0)
        bitL[t] = (t == 0) ? 1.0f : (float)trg[b*1024 + t - 1];

    // --- this thread's K-quarter of 3 gate rows into registers (f16 packed) ---
    h2 wR[32], wZ[32], wN[32];
    {
        const float2* wr = (const float2*)(w_hh + (size_t)d*256       + q*64);
        const float2* wz = (const float2*)(w_hh + (size_t)(d+256)*256 + q*64);
        const float2* wn = (const float2*)(w_hh + (size_t)(d+512)*256 + q*64);
        #pragma unroll
        for (int k = 0; k < 32; ++k) {
            float2 a = wr[k]; wR[k] = h2{(_Float16)a.x, (_Float16)a.y};
            float2 c = wz[k]; wZ[k] = h2{(_Float16)c.x, (_Float16)c.y};
            float2 e = wn[k]; wN[k] = h2{(_Float16)e.x, (_Float16)e.y};
        }
    }
    float bhr = b_hh[d], bhz = b_hh[256 + d], bhn = b_hh[512 + d];
    float wir=0.f, wiz=0.f, win=0.f, bir=0.f, biz=0.f, bin=0.f;
    if (LAYER == 0) {
        wir = w_ih0[d]; wiz = w_ih0[256 + d]; win = w_ih0[512 + d];
        bir = b_ih0[d]; biz = b_ih0[256 + d]; bin = b_ih0[512 + d];
    }

    float hreg = sh[b*256 + d];
    if (q == 0) hbuf[0][hperm(d)] = (_Float16)hreg;

    float xr, xz, xn;
    if (LAYER == 1) {
        size_t base = (size_t)b*768;
        xr = xp1[base + d]; xz = xp1[base + 256 + d]; xn = xp1[base + 512 + d];
    }
    __syncthreads();

    for (int l = 0; l < 1024; ++l) {
        // prefetch next step's xp (consumed next iteration; stays in flight
        // across the lgkm-only barrier)
        float nxr, nxz, nxn;
        if (LAYER == 1) {
            int ln = (l < 1023) ? (l + 1) : 1023;
            size_t base = ((size_t)ln*32 + b)*768;
            nxr = xp1[base + d]; nxz = xp1[base + 256 + d]; nxn = xp1[base + 512 + d];
        }
        // --- partial dots over this thread's K-quarter ---
        const float4* hb4 = (const float4*)(&hbuf[l & 1][0]);
        float ar = 0.f, az = 0.f, an = 0.f;
        #pragma unroll
        for (int kk = 0; kk < 8; ++kk) {
            float4 hv = hb4[kk*4 + q];              // dims q*64+kk*8 .. +8
            h2 h0 = __builtin_bit_cast(h2, hv.x);
            h2 h1 = __builtin_bit_cast(h2, hv.y);
            h2 hc = __builtin_bit_cast(h2, hv.z);
            h2 h3 = __builtin_bit_cast(h2, hv.w);
            ar = dot2(wR[4*kk+0], h0, ar); ar = dot2(wR[4*kk+1], h1, ar);
            ar = dot2(wR[4*kk+2], hc, ar); ar = dot2(wR[4*kk+3], h3, ar);
            az = dot2(wZ[4*kk+0], h0, az); az = dot2(wZ[4*kk+1], h1, az);
            az = dot2(wZ[4*kk+2], hc, az); az = dot2(wZ[4*kk+3], h3, az);
            an = dot2(wN[4*kk+0], h0, an); an = dot2(wN[4*kk+1], h1, an);
            an = dot2(wN[4*kk+2], hc, an); an = dot2(wN[4*kk+3], h3, an);
        }
        // combine quarters (quad-local butterflies)
        ar += __shfl_xor(ar, 1); ar += __shfl_xor(ar, 2);
        az += __shfl_xor(az, 1); az += __shfl_xor(az, 2);
        an += __shfl_xor(an, 1); an += __shfl_xor(an, 2);
        // --- gates (all 4 quad lanes compute identically) ---
        if (LAYER == 0) {
            float bit = bitL[l];
            xr = bir + bit*wir; xz = biz + bit*wiz; xn = bin + bit*win;
        }
        float r = sigm(xr + ar + bhr);
        float z = sigm(xz + az + bhz);
        float n = tanhf(xn + r*(an + bhn));
        hreg = (1.0f - z)*n + z*hreg;
        if (q == 0) {
            hbuf[(l + 1) & 1][hperm(d)] = (_Float16)hreg;
        } else if (q == 1) {
            size_t oidx = (LAYER == 0) ? (((size_t)l*32 + b)*256 + d)
                                       : (((size_t)b*1024 + l)*256 + d);
            out[oidx] = hreg;
        }
        wg_barrier();
        if (LAYER == 1) { xr = nxr; xz = nxz; xn = nxn; }
    }
}

// ---------------- generic fp32 GEMM: C[M,N] = act(A[M,K] @ B[N,K]^T + bias) ----------------
// aMode 0: plain A. aMode 3 (comb): K=768, k<256 -> A(ctx), k<512 -> A1(outs), else A2(sh, row=m>>10)
__global__ __launch_bounds__(256) void k_gemm(
    const float* __restrict__ A, const float* __restrict__ B,
    const float* __restrict__ bias, float* __restrict__ C,
    int M, int N, int K, int act, int aMode,
    const float* __restrict__ A1, const float* __restrict__ A2)
{
    __shared__ __align__(16) float As[16][128];
    __shared__ __align__(16) float Bs[16][128];
    int nbn = N >> 7;
    int bx = blockIdx.x % nbn, by = blockIdx.x / nbn;
    int m0 = by << 7, n0 = bx << 7;
    int t = threadIdx.x;
    int tm = t >> 4, tn = t & 15;
    float acc[8][8] = {};
    for (int kt = 0; kt < K; kt += 16) {
        __syncthreads();
        #pragma unroll
        for (int idx = t; idx < 512; idx += 256) {
            int m = idx >> 2, kc = idx & 3;
            int gk = kt + (kc << 2);
            float4 va;
            if (aMode == 0) {
                va = *(const float4*)(A + (size_t)(m0+m)*K + gk);
            } else {
                int part = gk >> 8, kk = gk & 255;
                const float* P = (part == 0) ? A : ((part == 1) ? A1 : A2);
                int row = (part == 2) ? ((m0+m) >> 10) : (m0+m);
                va = *(const float4*)(P + (size_t)row*256 + kk);
            }
            int kb = kc << 2;
            As[kb+0][m]=va.x; As[kb+1][m]=va.y; As[kb+2][m]=va.z; As[kb+3][m]=va.w;
            float4 vb = *(const float4*)(B + (size_t)(n0+m)*K + gk);
            Bs[kb+0][m]=vb.x; Bs[kb+1][m]=vb.y; Bs[kb+2][m]=vb.z; Bs[kb+3][m]=vb.w;
        }
        __syncthreads();
        #pragma unroll
        for (int k = 0; k < 16; ++k) {
            float4 a0 = *(const float4*)&As[k][tm*8];
            float4 a1 = *(const float4*)&As[k][tm*8+4];
            float4 q0 = *(const float4*)&Bs[k][tn*8];
            float4 q1 = *(const float4*)&Bs[k][tn*8+4];
            float av[8] = {a0.x,a0.y,a0.z,a0.w,a1.x,a1.y,a1.z,a1.w};
            float bv[8] = {q0.x,q0.y,q0.z,q0.w,q1.x,q1.y,q1.z,q1.w};
            #pragma unroll
            for (int i = 0; i < 8; ++i)
                #pragma unroll
                for (int j = 0; j < 8; ++j)
                    acc[i][j] += av[i]*bv[j];
        }
    }
    float bv[8];
    #pragma unroll
    for (int j = 0; j < 8; ++j) bv[j] = bias[n0 + tn*8 + j];
    #pragma unroll
    for (int i = 0; i < 8; ++i) {
        size_t row = (size_t)(m0 + tm*8 + i);
        float o[8];
        #pragma unroll
        for (int j = 0; j < 8; ++j) {
            float v = acc[i][j] + bv[j];
            if (act == 1) v = geluf(v);
            else if (act == 2) v = tanhf(v);
            o[j] = v;
        }
        float4* cp = (float4*)(C + row*N + n0 + tn*8);
        cp[0] = make_float4(o[0],o[1],o[2],o[3]);
        cp[1] = make_float4(o[4],o[5],o[6],o[7]);
    }
}

// ---------------- causal attention (flash-style), WG = (b, 16 rows) ----------------
__global__ __launch_bounds__(256) void k_attn(
    const float* __restrict__ outs, const float* __restrict__ modif, float* __restrict__ ctx)
{
    __shared__ __align__(16) float Qs[16][256];
    __shared__ __align__(16) float KVs[32][256];
    __shared__ __align__(16) float sS[16][32];
    __shared__ float rowScaleL[16];
    __shared__ float rowLL[16];
    int b = blockIdx.y, l0 = blockIdx.x << 4, t = threadIdx.x;
    for (int idx = t; idx < 1024; idx += 256) {
        int r = idx >> 6, k4 = idx & 63;
        *(float4*)&Qs[r][k4*4] = *(const float4*)(outs + ((size_t)b*1024 + l0 + r)*256 + k4*4);
    }
    int sr = t >> 4, sj = t & 15;          // softmax grouping
    int rp = t >> 5, cg = t & 31;          // PV grouping: rows 2rp,2rp+1; cols cg*8
    float rowM = -1e30f, rowL = 0.f;
    float accA[8] = {}, accB[8] = {};
    int nt = ((l0 + 14) >> 5) + 1;
    for (int tt = 0; tt < nt; ++tt) {
        int m0 = tt << 5;
        __syncthreads();
        for (int idx = t; idx < 2048; idx += 256) {      // stage K = modif rows
            int mm = idx >> 6, k4 = idx & 63;
            *(float4*)&KVs[mm][k4*4] = *(const float4*)(modif + ((size_t)b*1024 + m0 + mm)*256 + k4*4);
        }
        __syncthreads();
        {   // QK: thread -> (row sr, cols 2*sj, 2*sj+1)
            // k-loop rotated by sj so the 16 lanes of a row-group hit 8
            // distinct bank-quads per cycle
            int mp = sj << 1;
            const float4* q4 = (const float4*)Qs[sr];
            const float4* x4 = (const float4*)KVs[mp];
            const float4* y4 = (const float4*)KVs[mp+1];
            float s0 = 0.f, s1 = 0.f;
            #pragma unroll 8
            for (int kk = 0; kk < 64; ++kk) {
                int k = (kk + sj) & 63;
                float4 q = q4[k], x = x4[k], y = y4[k];
                s0 += q.x*x.x + q.y*x.y + q.z*x.z + q.w*x.w;
                s1 += q.x*y.x + q.y*y.y + q.z*y.z + q.w*y.w;
            }
            int l = l0 + sr;
            if (m0 + mp     >= l) s0 = -1e30f;
            if (m0 + mp + 1 >= l) s1 = -1e30f;
            sS[sr][mp] = s0; sS[sr][mp+1] = s1;
        }
        __syncthreads();
        {   // online softmax update
            float v0 = sS[sr][sj], v1 = sS[sr][sj+16];
            float mx = fmaxf(v0, v1);
            for (int off = 8; off; off >>= 1) mx = fmaxf(mx, __shfl_xor(mx, off));
            float newM = fmaxf(rowM, mx);
            float scale, p0, p1;
            if (newM < -1e29f) { scale = 1.f; p0 = 0.f; p1 = 0.f; }
            else { scale = expf(rowM - newM); p0 = expf(v0 - newM); p1 = expf(v1 - newM); }
            rowM = newM;
            float ts = p0 + p1;
            for (int off = 8; off; off >>= 1) ts += __shfl_xor(ts, off);
            rowL = rowL*scale + ts;
            sS[sr][sj] = p0; sS[sr][sj+16] = p1;
            if (sj == 0) { rowScaleL[sr] = scale; rowLL[sr] = rowL; }
        }
        __syncthreads();
        for (int idx = t; idx < 2048; idx += 256) {      // stage V = outs rows
            int mm = idx >> 6, k4 = idx & 63;
            *(float4*)&KVs[mm][k4*4] = *(const float4*)(outs + ((size_t)b*1024 + m0 + mm)*256 + k4*4);
        }
        __syncthreads();
        {   // PV accumulate
            float sc0 = rowScaleL[2*rp], sc1 = rowScaleL[2*rp+1];
            #pragma unroll
            for (int j = 0; j < 8; ++j) { accA[j] *= sc0; accB[j] *= sc1; }
            int c0 = cg << 3;
            #pragma unroll 4
            for (int mm = 0; mm < 32; ++mm) {
                float p0 = sS[2*rp][mm], p1 = sS[2*rp+1][mm];
                float4 vA = *(const float4*)&KVs[mm][c0];
                float4 vB = *(const float4*)&KVs[mm][c0+4];
                accA[0] += p0*vA.x; accA[1] += p0*vA.y; accA[2] += p0*vA.z; accA[3] += p0*vA.w;
                accA[4] += p0*vB.x; accA[5] += p0*vB.y; accA[6] += p0*vB.z; accA[7] += p0*vB.w;
                accB[0] += p1*vA.x; accB[1] += p1*vA.y; accB[2] += p1*vA.z; accB[3] += p1*vA.w;
                accB[4] += p1*vB.x; accB[5] += p1*vB.y; accB[6] += p1*vB.z; accB[7] += p1*vB.w;
            }
        }
    }
    __syncthreads();
    int c0 = cg << 3;
    {
        int l = l0 + 2*rp;
        float inv = (l == 0) ? 0.f : 1.f/rowLL[2*rp];
        float4* cp = (float4*)(ctx + ((size_t)b*1024 + l)*256 + c0);
        cp[0] = make_float4(accA[0]*inv, accA[1]*inv, accA[2]*inv, accA[3]*inv);
        cp[1] = make_float4(accA[4]*inv, accA[5]*inv, accA[6]*inv, accA[7]*inv);
    }
    {
        int l = l0 + 2*rp + 1;
        float inv = 1.f/rowLL[2*rp+1];
        float4* cp = (float4*)(ctx + ((size_t)b*1024 + l)*256 + c0);
        cp[0] = make_float4(accB[0]*inv, accB[1]*inv, accB[2]*inv, accB[3]*inv);
        cp[1] = make_float4(accB[4]*inv, accB[5]*inv, accB[6]*inv, accB[7]*inv);
    }
}

// ---------------- final: logits + outputs ----------------
__global__ __launch_bounds__(256) void k_final(
    const float* __restrict__ h2v, const float* __restrict__ w2, const float* __restrict__ b2,
    const float* __restrict__ mask, float* __restrict__ out)
{
    int i = blockIdx.x*256 + threadIdx.x;   // < 32768
    const float4* h4 = (const float4*)(h2v + (size_t)i*256);
    const float4* w4 = (const float4*)w2;
    float a0=0,a1=0,a2=0,a3=0;
    #pragma unroll 8
    for (int k = 0; k < 64; ++k) {
        float4 h = h4[k], w = w4[k];
        a0 += h.x*w.x; a1 += h.y*w.y; a2 += h.z*w.z; a3 += h.w*w.w;
    }
    float lg = a0+a1+a2+a3 + b2[0];
    float p = sigm(lg);
    out[2*i]     = 1.0f - p;
    out[2*i + 1] = p;
    out[65536  + i] = (lg > 0.f) ? 1.0f : ((lg < 0.f) ? -1.0f : 0.0f);
    out[98304  + i] = mask[i];
    out[131072 + i] = lg;
}

extern "C" void kernel_launch(void* const* d_in, const int* in_sizes, int n_in,
                              void* d_out, int out_size, void* d_ws, size_t ws_size,
                              hipStream_t stream)
{
    const float* ne      = (const float*)d_in[0];
    const float* mask    = (const float*)d_in[1];
    const int*   trg     = (const int*)  d_in[2];
    const float* se_w0   = (const float*)d_in[3];
    const float* se_b0   = (const float*)d_in[4];
    const float* se_w1   = (const float*)d_in[5];
    const float* se_b1   = (const float*)d_in[6];
    const float* se_w2   = (const float*)d_in[7];
    const float* se_b2   = (const float*)d_in[8];
    const float* w_ih0   = (const float*)d_in[9];
    const float* w_hh0   = (const float*)d_in[10];
    const float* b_ih0   = (const float*)d_in[11];
    const float* b_hh0   = (const float*)d_in[12];
    const float* w_ih1   = (const float*)d_in[13];
    const float* w_hh1   = (const float*)d_in[14];
    const float* b_ih1   = (const float*)d_in[15];
    const float* b_hh1   = (const float*)d_in[16];
    const float* attn_w1 = (const float*)d_in[17];
    const float* attn_b1 = (const float*)d_in[18];
    const float* comb_w  = (const float*)d_in[19];
    const float* comb_b  = (const float*)d_in[20];
    const float* dec_w0  = (const float*)d_in[21];
    const float* dec_b0  = (const float*)d_in[22];
    const float* dec_w1  = (const float*)d_in[23];
    const float* dec_b1  = (const float*)d_in[24];
    const float* dec_w2  = (const float*)d_in[25];
    const float* dec_b2  = (const float*)d_in[26];

    float* W    = (float*)d_ws;
    float* sh   = W;                    // 8192
    float* o0   = W + 8192;             // [L,B,D] 8388608
    float* xp1  = W + 8396800;          // [L,B,G] 25165824
    float* outs = W + 33562624;         // [B,L,D] 8388608  (total 41951232 floats = 160 MB)
    float* modif = o0;                  // reuse (o0 dead after xp1 GEMM)
    float* ctx  = xp1;                  // reuse (xp1 dead after scan1)
    float* dec  = xp1 + 8388608;
    float* h1   = xp1 + 16777216;
    float* h2b  = o0;                   // reuse (modif dead after attention)
    float* out  = (float*)d_out;

    k_start_embed<<<32, 256, 0, stream>>>(ne, se_w0, se_b0, se_w1, se_b1, se_w2, se_b2, sh);
    k_gru_scan<0><<<32, 1024, 0, stream>>>(w_hh0, b_hh0, w_ih0, b_ih0, nullptr, trg, sh, o0);
    k_gemm<<<1536, 256, 0, stream>>>(o0, w_ih1, b_ih1, xp1, NROWS, 768, 256, 0, 0, nullptr, nullptr);
    k_gru_scan<1><<<32, 1024, 0, stream>>>(w_hh1, b_hh1, nullptr, nullptr, xp1, trg, sh, outs);
    k_gemm<<<512, 256, 0, stream>>>(outs, attn_w1, attn_b1, modif, NROWS, 256, 256, 0, 0, nullptr, nullptr);
    { dim3 ag(64, 32); k_attn<<<ag, 256, 0, stream>>>(outs, modif, ctx); }
    k_gemm<<<512, 256, 0, stream>>>(ctx, comb_w, comb_b, dec, NROWS, 256, 768, 2, 3, outs, sh);
    k_gemm<<<512, 256, 0, stream>>>(dec, dec_w0, dec_b0, h1, NROWS, 256, 256, 1, 0, nullptr, nullptr);
    k_gemm<<<512, 256, 0, stream>>>(h1, dec_w1, dec_b1, h2b, NROWS, 256, 256, 1, 0, nullptr, nullptr);
    k_final<<<128, 256, 0, stream>>>(h2b, dec_w2, dec_b2, mask, out);
}

// Round 6
// 3988.725 us; speedup vs baseline: 1.1818x; 1.1818x over previous
//
#include <hip/hip_runtime.h>
#include <math.h>

// B=32, L=1024, D=256, G=768
#define NROWS 32768  // B*L

typedef float v4 __attribute__((ext_vector_type(4)));
typedef _Float16 h2 __attribute__((ext_vector_type(2)));

__device__ __forceinline__ float geluf(float x){ return 0.5f*x*(1.0f+erff(x*0.70710678118654752f)); }
__device__ __forceinline__ float sigm(float x){ return 1.0f/(1.0f+expf(-x)); }

__device__ __forceinline__ float dot2(h2 a, h2 b, float c){
#if __has_builtin(__builtin_amdgcn_fdot2)
    return __builtin_amdgcn_fdot2(a, b, c, false);
#else
    return c + (float)a.x*(float)b.x + (float)a.y*(float)b.y;
#endif
}

// barrier that does NOT drain vmcnt: LDS visibility only. Global prefetch
// loads / output stores stay in flight across it.
__device__ __forceinline__ void wg_barrier(){
    asm volatile("s_waitcnt lgkmcnt(0)" ::: "memory");
    __builtin_amdgcn_s_barrier();
    __builtin_amdgcn_sched_barrier(0);
}

// ---------------- start embed: sh[b,d] ----------------
__global__ __launch_bounds__(256) void k_start_embed(
    const float* __restrict__ ne, const float* __restrict__ w0, const float* __restrict__ b0,
    const float* __restrict__ w1, const float* __restrict__ b1,
    const float* __restrict__ w2, const float* __restrict__ b2,
    float* __restrict__ sh)
{
    __shared__ __align__(16) float encL[1024];
    __shared__ __align__(16) float g1[256];
    __shared__ __align__(16) float g2[256];
    int b = blockIdx.x, t = threadIdx.x;
    for (int i = t; i < 1024; i += 256) encL[i] = ne[b*1024 + i];
    __syncthreads();
    const float4* wr = (const float4*)(w0 + (size_t)t*1024);
    const float4* e4 = (const float4*)encL;
    float a0=0,a1=0,a2=0,a3=0;
    #pragma unroll 8
    for (int k = 0; k < 256; ++k){ float4 w = wr[k], e = e4[k];
        a0 += w.x*e.x; a1 += w.y*e.y; a2 += w.z*e.z; a3 += w.w*e.w; }
    float t1 = a0+a1+a2+a3 + b0[t];
    float res = t1;
    g1[t] = geluf(t1);
    __syncthreads();
    const float4* w1r = (const float4*)(w1 + (size_t)t*256);
    const float4* g14 = (const float4*)g1;
    a0=a1=a2=a3=0.f;
    #pragma unroll 8
    for (int k = 0; k < 64; ++k){ float4 w = w1r[k], e = g14[k];
        a0 += w.x*e.x; a1 += w.y*e.y; a2 += w.z*e.z; a3 += w.w*e.w; }
    g2[t] = geluf(a0+a1+a2+a3 + b1[t]);
    __syncthreads();
    const float4* w2r = (const float4*)(w2 + (size_t)t*256);
    const float4* g24 = (const float4*)g2;
    a0=a1=a2=a3=0.f;
    #pragma unroll 8
    for (int k = 0; k < 64; ++k){ float4 w = w2r[k], e = g24[k];
        a0 += w.x*e.x; a1 += w.y*e.y; a2 += w.z*e.z; a3 += w.w*e.w; }
    sh[b*256 + t] = a0+a1+a2+a3 + b2[t] + res;
}

// permuted f16 index within an hbuf row for hidden dim:
// dim = (hi:2)(mid:3)(lo:3) -> idx = mid*32 + hi*8 + lo  (bijective).
// Float4 slot s = mid*4 + hi holds dims hi*64 + mid*8 .. +8. K-half reads
// become 2-address wave broadcasts; writes are 2-way (free).
__device__ __forceinline__ int hperm(int dim){
    return ((dim >> 3) & 7)*32 + ((dim >> 6) << 3) + (dim & 7);
}

// ---------------- GRU scan v6: register-resident f16 weights, K-half split ----------------
// One WG per batch, 512 threads. amdgpu_waves_per_eu(2,2) PINS the allocator
// at exactly 2 waves/SIMD -> 256-VGPR budget (R3/R4/R5 showed launch_bounds
// alone lets the occupancy heuristic pick a lower target and spill the
// weight arrays). Thread (d = t>>1, half = t&1) owns gate rows d (r),
// d+256 (z), d+512 (n) over K-half [half*128, +128): 3 x 64 h2 = 192 weight
// VGPRs + ~50 state < 256 -> no spill. Pair partials combined with one
// __shfl_xor(.,1) per gate. h kept f16 in LDS (hperm layout), fp32 master h
// in a register; one lgkm-only barrier per step.
template<int LAYER>
__global__
__attribute__((amdgpu_flat_work_group_size(512, 512), amdgpu_waves_per_eu(2, 2)))
void k_gru_scan(
    const float* __restrict__ w_hh, const float* __restrict__ b_hh,
    const float* __restrict__ w_ih0, const float* __restrict__ b_ih0,
    const float* __restrict__ xp1,
    const int*   __restrict__ trg,
    const float* __restrict__ sh,
    float* __restrict__ out)
{
    __shared__ __align__(16) _Float16 hbuf[2][256];
    __shared__ __align__(16) float bitL[1024];
    int b = blockIdx.x, t = threadIdx.x;
    int d = t >> 1, half = t & 1;

    if (LAYER == 0) {
        #pragma unroll
        for (int i = 0; i < 2; ++i) {
            int idx = t + i*512;
            bitL[idx] = (idx == 0) ? 1.0f : (float)trg[b*1024 + idx - 1];
        }
    }

    // --- this thread's K-half of 3 gate rows into registers (f16 packed) ---
    h2 wR[64], wZ[64], wN[64];
    {
        const float2* wr = (const float2*)(w_hh + (size_t)d*256       + half*128);
        const float2* wz = (const float2*)(w_hh + (size_t)(d+256)*256 + half*128);
        const float2* wn = (const float2*)(w_hh + (size_t)(d+512)*256 + half*128);
        #pragma unroll
        for (int k = 0; k < 64; ++k) {
            float2 a = wr[k]; wR[k] = h2{(_Float16)a.x, (_Float16)a.y};
            float2 c = wz[k]; wZ[k] = h2{(_Float16)c.x, (_Float16)c.y};
            float2 e = wn[k]; wN[k] = h2{(_Float16)e.x, (_Float16)e.y};
        }
    }
    float bhr = b_hh[d], bhz = b_hh[256 + d], bhn = b_hh[512 + d];
    float wir=0.f, wiz=0.f, win=0.f, bir=0.f, biz=0.f, bin=0.f;
    if (LAYER == 0) {
        wir = w_ih0[d]; wiz = w_ih0[256 + d]; win = w_ih0[512 + d];
        bir = b_ih0[d]; biz = b_ih0[256 + d]; bin = b_ih0[512 + d];
    }

    float hreg = sh[b*256 + d];
    if (half == 0) hbuf[0][hperm(d)] = (_Float16)hreg;

    float xr, xz, xn;
    if (LAYER == 1) {
        size_t base = (size_t)b*768;
        xr = xp1[base + d]; xz = xp1[base + 256 + d]; xn = xp1[base + 512 + d];
    }
    __syncthreads();

    for (int l = 0; l < 1024; ++l) {
        // prefetch next step's xp (stays in flight across the lgkm-only barrier)
        float nxr, nxz, nxn;
        if (LAYER == 1) {
            int ln = (l < 1023) ? (l + 1) : 1023;
            size_t base = ((size_t)ln*32 + b)*768;
            nxr = xp1[base + d]; nxz = xp1[base + 256 + d]; nxn = xp1[base + 512 + d];
        }
        // --- partial dots over this thread's K-half ---
        const float4* hb4 = (const float4*)(&hbuf[l & 1][0]);
        float ar = 0.f, az = 0.f, an = 0.f;
        #pragma unroll
        for (int kk = 0; kk < 16; ++kk) {
            // permuted slot holding dims half*128 + kk*8 .. +8
            float4 hv = hb4[(kk & 7)*4 + half*2 + (kk >> 3)];
            h2 h0 = __builtin_bit_cast(h2, hv.x);
            h2 h1 = __builtin_bit_cast(h2, hv.y);
            h2 hc = __builtin_bit_cast(h2, hv.z);
            h2 h3 = __builtin_bit_cast(h2, hv.w);
            ar = dot2(wR[4*kk+0], h0, ar); ar = dot2(wR[4*kk+1], h1, ar);
            ar = dot2(wR[4*kk+2], hc, ar); ar = dot2(wR[4*kk+3], h3, ar);
            az = dot2(wZ[4*kk+0], h0, az); az = dot2(wZ[4*kk+1], h1, az);
            az = dot2(wZ[4*kk+2], hc, az); az = dot2(wZ[4*kk+3], h3, az);
            an = dot2(wN[4*kk+0], h0, an); an = dot2(wN[4*kk+1], h1, an);
            an = dot2(wN[4*kk+2], hc, an); an = dot2(wN[4*kk+3], h3, an);
        }
        // combine K-halves (partner = lane^1, same wave)
        ar += __shfl_xor(ar, 1);
        az += __shfl_xor(az, 1);
        an += __shfl_xor(an, 1);
        // --- gates (both lanes of the pair compute identically) ---
        if (LAYER == 0) {
            float bit = bitL[l];
            xr = bir + bit*wir; xz = biz + bit*wiz; xn = bin + bit*win;
        }
        float r = sigm(xr + ar + bhr);
        float z = sigm(xz + az + bhz);
        float n = tanhf(xn + r*(an + bhn));
        hreg = (1.0f - z)*n + z*hreg;
        if (half == 0) {
            hbuf[(l + 1) & 1][hperm(d)] = (_Float16)hreg;
        } else {
            size_t oidx = (LAYER == 0) ? (((size_t)l*32 + b)*256 + d)
                                       : (((size_t)b*1024 + l)*256 + d);
            out[oidx] = hreg;
        }
        wg_barrier();
        if (LAYER == 1) { xr = nxr; xz = nxz; xn = nxn; }
    }
}

// ---------------- generic fp32 GEMM: C[M,N] = act(A[M,K] @ B[N,K]^T + bias) ----------------
// aMode 0: plain A. aMode 3 (comb): K=768, k<256 -> A(ctx), k<512 -> A1(outs), else A2(sh, row=m>>10)
__global__ __launch_bounds__(256) void k_gemm(
    const float* __restrict__ A, const float* __restrict__ B,
    const float* __restrict__ bias, float* __restrict__ C,
    int M, int N, int K, int act, int aMode,
    const float* __restrict__ A1, const float* __restrict__ A2)
{
    __shared__ __align__(16) float As[16][128];
    __shared__ __align__(16) float Bs[16][128];
    int nbn = N >> 7;
    int bx = blockIdx.x % nbn, by = blockIdx.x / nbn;
    int m0 = by << 7, n0 = bx << 7;
    int t = threadIdx.x;
    int tm = t >> 4, tn = t & 15;
    float acc[8][8] = {};
    for (int kt = 0; kt < K; kt += 16) {
        __syncthreads();
        #pragma unroll
        for (int idx = t; idx < 512; idx += 256) {
            int m = idx >> 2, kc = idx & 3;
            int gk = kt + (kc << 2);
            float4 va;
            if (aMode == 0) {
                va = *(const float4*)(A + (size_t)(m0+m)*K + gk);
            } else {
                int part = gk >> 8, kk = gk & 255;
                const float* P = (part == 0) ? A : ((part == 1) ? A1 : A2);
                int row = (part == 2) ? ((m0+m) >> 10) : (m0+m);
                va = *(const float4*)(P + (size_t)row*256 + kk);
            }
            int kb = kc << 2;
            As[kb+0][m]=va.x; As[kb+1][m]=va.y; As[kb+2][m]=va.z; As[kb+3][m]=va.w;
            float4 vb = *(const float4*)(B + (size_t)(n0+m)*K + gk);
            Bs[kb+0][m]=vb.x; Bs[kb+1][m]=vb.y; Bs[kb+2][m]=vb.z; Bs[kb+3][m]=vb.w;
        }
        __syncthreads();
        #pragma unroll
        for (int k = 0; k < 16; ++k) {
            float4 a0 = *(const float4*)&As[k][tm*8];
            float4 a1 = *(const float4*)&As[k][tm*8+4];
            float4 q0 = *(const float4*)&Bs[k][tn*8];
            float4 q1 = *(const float4*)&Bs[k][tn*8+4];
            float av[8] = {a0.x,a0.y,a0.z,a0.w,a1.x,a1.y,a1.z,a1.w};
            float bv[8] = {q0.x,q0.y,q0.z,q0.w,q1.x,q1.y,q1.z,q1.w};
            #pragma unroll
            for (int i = 0; i < 8; ++i)
                #pragma unroll
                for (int j = 0; j < 8; ++j)
                    acc[i][j] += av[i]*bv[j];
        }
    }
    float bv[8];
    #pragma unroll
    for (int j = 0; j < 8; ++j) bv[j] = bias[n0 + tn*8 + j];
    #pragma unroll
    for (int i = 0; i < 8; ++i) {
        size_t row = (size_t)(m0 + tm*8 + i);
        float o[8];
        #pragma unroll
        for (int j = 0; j < 8; ++j) {
            float v = acc[i][j] + bv[j];
            if (act == 1) v = geluf(v);
            else if (act == 2) v = tanhf(v);
            o[j] = v;
        }
        float4* cp = (float4*)(C + row*N + n0 + tn*8);
        cp[0] = make_float4(o[0],o[1],o[2],o[3]);
        cp[1] = make_float4(o[4],o[5],o[6],o[7]);
    }
}

// ---------------- causal attention (flash-style), WG = (b, 16 rows) ----------------
__global__ __launch_bounds__(256) void k_attn(
    const float* __restrict__ outs, const float* __restrict__ modif, float* __restrict__ ctx)
{
    __shared__ __align__(16) float Qs[16][256];
    __shared__ __align__(16) float KVs[32][256];
    __shared__ __align__(16) float sS[16][32];
    __shared__ float rowScaleL[16];
    __shared__ float rowLL[16];
    int b = blockIdx.y, l0 = blockIdx.x << 4, t = threadIdx.x;
    for (int idx = t; idx < 1024; idx += 256) {
        int r = idx >> 6, k4 = idx & 63;
        *(float4*)&Qs[r][k4*4] = *(const float4*)(outs + ((size_t)b*1024 + l0 + r)*256 + k4*4);
    }
    int sr = t >> 4, sj = t & 15;          // softmax grouping
    int rp = t >> 5, cg = t & 31;          // PV grouping: rows 2rp,2rp+1; cols cg*8
    float rowM = -1e30f, rowL = 0.f;
    float accA[8] = {}, accB[8] = {};
    int nt = ((l0 + 14) >> 5) + 1;
    for (int tt = 0; tt < nt; ++tt) {
        int m0 = tt << 5;
        __syncthreads();
        for (int idx = t; idx < 2048; idx += 256) {      // stage K = modif rows
            int mm = idx >> 6, k4 = idx & 63;
            *(float4*)&KVs[mm][k4*4] = *(const float4*)(modif + ((size_t)b*1024 + m0 + mm)*256 + k4*4);
        }
        __syncthreads();
        {   // QK: thread -> (row sr, cols 2*sj, 2*sj+1)
            // k-loop rotated by sj so the 16 lanes of a row-group hit 8
            // distinct bank-quads per cycle
            int mp = sj << 1;
            const float4* q4 = (const float4*)Qs[sr];
            const float4* x4 = (const float4*)KVs[mp];
            const float4* y4 = (const float4*)KVs[mp+1];
            float s0 = 0.f, s1 = 0.f;
            #pragma unroll 8
            for (int kk = 0; kk < 64; ++kk) {
                int k = (kk + sj) & 63;
                float4 q = q4[k], x = x4[k], y = y4[k];
                s0 += q.x*x.x + q.y*x.y + q.z*x.z + q.w*x.w;
                s1 += q.x*y.x + q.y*y.y + q.z*y.z + q.w*y.w;
            }
            int l = l0 + sr;
            if (m0 + mp     >= l) s0 = -1e30f;
            if (m0 + mp + 1 >= l) s1 = -1e30f;
            sS[sr][mp] = s0; sS[sr][mp+1] = s1;
        }
        __syncthreads();
        {   // online softmax update
            float v0 = sS[sr][sj], v1 = sS[sr][sj+16];
            float mx = fmaxf(v0, v1);
            for (int off = 8; off; off >>= 1) mx = fmaxf(mx, __shfl_xor(mx, off));
            float newM = fmaxf(rowM, mx);
            float scale, p0, p1;
            if (newM < -1e29f) { scale = 1.f; p0 = 0.f; p1 = 0.f; }
            else { scale = expf(rowM - newM); p0 = expf(v0 - newM); p1 = expf(v1 - newM); }
            rowM = newM;
            float ts = p0 + p1;
            for (int off = 8; off; off >>= 1) ts += __shfl_xor(ts, off);
            rowL = rowL*scale + ts;
            sS[sr][sj] = p0; sS[sr][sj+16] = p1;
            if (sj == 0) { rowScaleL[sr] = scale; rowLL[sr] = rowL; }
        }
        __syncthreads();
        for (int idx = t; idx < 2048; idx += 256) {      // stage V = outs rows
            int mm = idx >> 6, k4 = idx & 63;
            *(float4*)&KVs[mm][k4*4] = *(const float4*)(outs + ((size_t)b*1024 + m0 + mm)*256 + k4*4);
        }
        __syncthreads();
        {   // PV accumulate
            float sc0 = rowScaleL[2*rp], sc1 = rowScaleL[2*rp+1];
            #pragma unroll
            for (int j = 0; j < 8; ++j) { accA[j] *= sc0; accB[j] *= sc1; }
            int c0 = cg << 3;
            #pragma unroll 4
            for (int mm = 0; mm < 32; ++mm) {
                float p0 = sS[2*rp][mm], p1 = sS[2*rp+1][mm];
                float4 vA = *(const float4*)&KVs[mm][c0];
                float4 vB = *(const float4*)&KVs[mm][c0+4];
                accA[0] += p0*vA.x; accA[1] += p0*vA.y; accA[2] += p0*vA.z; accA[3] += p0*vA.w;
                accA[4] += p0*vB.x; accA[5] += p0*vB.y; accA[6] += p0*vB.z; accA[7] += p0*vB.w;
                accB[0] += p1*vA.x; accB[1] += p1*vA.y; accB[2] += p1*vA.z; accB[3] += p1*vA.w;
                accB[4] += p1*vB.x; accB[5] += p1*vB.y; accB[6] += p1*vB.z; accB[7] += p1*vB.w;
            }
        }
    }
    __syncthreads();
    int c0 = cg << 3;
    {
        int l = l0 + 2*rp;
        float inv = (l == 0) ? 0.f : 1.f/rowLL[2*rp];
        float4* cp = (float4*)(ctx + ((size_t)b*1024 + l)*256 + c0);
        cp[0] = make_float4(accA[0]*inv, accA[1]*inv, accA[2]*inv, accA[3]*inv);
        cp[1] = make_float4(accA[4]*inv, accA[5]*inv, accA[6]*inv, accA[7]*inv);
    }
    {
        int l = l0 + 2*rp + 1;
        float inv = 1.f/rowLL[2*rp+1];
        float4* cp = (float4*)(ctx + ((size_t)b*1024 + l)*256 + c0);
        cp[0] = make_float4(accB[0]*inv, accB[1]*inv, accB[2]*inv, accB[3]*inv);
        cp[1] = make_float4(accB[4]*inv, accB[5]*inv, accB[6]*inv, accB[7]*inv);
    }
}

// ---------------- final: logits + outputs ----------------
__global__ __launch_bounds__(256) void k_final(
    const float* __restrict__ h2v, const float* __restrict__ w2, const float* __restrict__ b2,
    const float* __restrict__ mask, float* __restrict__ out)
{
    int i = blockIdx.x*256 + threadIdx.x;   // < 32768
    const float4* h4 = (const float4*)(h2v + (size_t)i*256);
    const float4* w4 = (const float4*)w2;
    float a0=0,a1=0,a2=0,a3=0;
    #pragma unroll 8
    for (int k = 0; k < 64; ++k) {
        float4 h = h4[k], w = w4[k];
        a0 += h.x*w.x; a1 += h.y*w.y; a2 += h.z*w.z; a3 += h.w*w.w;
    }
    float lg = a0+a1+a2+a3 + b2[0];
    float p = sigm(lg);
    out[2*i]     = 1.0f - p;
    out[2*i + 1] = p;
    out[65536  + i] = (lg > 0.f) ? 1.0f : ((lg < 0.f) ? -1.0f : 0.0f);
    out[98304  + i] = mask[i];
    out[131072 + i] = lg;
}

extern "C" void kernel_launch(void* const* d_in, const int* in_sizes, int n_in,
                              void* d_out, int out_size, void* d_ws, size_t ws_size,
                              hipStream_t stream)
{
    const float* ne      = (const float*)d_in[0];
    const float* mask    = (const float*)d_in[1];
    const int*   trg     = (const int*)  d_in[2];
    const float* se_w0   = (const float*)d_in[3];
    const float* se_b0   = (const float*)d_in[4];
    const float* se_w1   = (const float*)d_in[5];
    const float* se_b1   = (const float*)d_in[6];
    const float* se_w2   = (const float*)d_in[7];
    const float* se_b2   = (const float*)d_in[8];
    const float* w_ih0   = (const float*)d_in[9];
    const float* w_hh0   = (const float*)d_in[10];
    const float* b_ih0   = (const float*)d_in[11];
    const float* b_hh0   = (const float*)d_in[12];
    const float* w_ih1   = (const float*)d_in[13];
    const float* w_hh1   = (const float*)d_in[14];
    const float* b_ih1   = (const float*)d_in[15];
    const float* b_hh1   = (const float*)d_in[16];
    const float* attn_w1 = (const float*)d_in[17];
    const float* attn_b1 = (const float*)d_in[18];
    const float* comb_w  = (const float*)d_in[19];
    const float* comb_b  = (const float*)d_in[20];
    const float* dec_w0  = (const float*)d_in[21];
    const float* dec_b0  = (const float*)d_in[22];
    const float* dec_w1  = (const float*)d_in[23];
    const float* dec_b1  = (const float*)d_in[24];
    const float* dec_w2  = (const float*)d_in[25];
    const float* dec_b2  = (const float*)d_in[26];

    float* W    = (float*)d_ws;
    float* sh   = W;                    // 8192
    float* o0   = W + 8192;             // [L,B,D] 8388608
    float* xp1  = W + 8396800;          // [L,B,G] 25165824
    float* outs = W + 33562624;         // [B,L,D] 8388608  (total 41951232 floats = 160 MB)
    float* modif = o0;                  // reuse (o0 dead after xp1 GEMM)
    float* ctx  = xp1;                  // reuse (xp1 dead after scan1)
    float* dec  = xp1 + 8388608;
    float* h1   = xp1 + 16777216;
    float* h2b  = o0;                   // reuse (modif dead after attention)
    float* out  = (float*)d_out;

    k_start_embed<<<32, 256, 0, stream>>>(ne, se_w0, se_b0, se_w1, se_b1, se_w2, se_b2, sh);
    k_gru_scan<0><<<32, 512, 0, stream>>>(w_hh0, b_hh0, w_ih0, b_ih0, nullptr, trg, sh, o0);
    k_gemm<<<1536, 256, 0, stream>>>(o0, w_ih1, b_ih1, xp1, NROWS, 768, 256, 0, 0, nullptr, nullptr);
    k_gru_scan<1><<<32, 512, 0, stream>>>(w_hh1, b_hh1, nullptr, nullptr, xp1, trg, sh, outs);
    k_gemm<<<512, 256, 0, stream>>>(outs, attn_w1, attn_b1, modif, NROWS, 256, 256, 0, 0, nullptr, nullptr);
    { dim3 ag(64, 32); k_attn<<<ag, 256, 0, stream>>>(outs, modif, ctx); }
    k_gemm<<<512, 256, 0, stream>>>(ctx, comb_w, comb_b, dec, NROWS, 256, 768, 2, 3, outs, sh);
    k_gemm<<<512, 256, 0, stream>>>(dec, dec_w0, dec_b0, h1, NROWS, 256, 256, 1, 0, nullptr, nullptr);
    k_gemm<<<512, 256, 0, stream>>>(h1, dec_w1, dec_b1, h2b, NROWS, 256, 256, 1, 0, nullptr, nullptr);
    k_final<<<128, 256, 0, stream>>>(h2b, dec_w2, dec_b2, mask, out);
}